// Round 10
// baseline (113.313 us; speedup 1.0000x reference)
//
#include <hip/hip_runtime.h>

// DSSIM = 1 - mean(SSIM), 11x11 gaussian (sigma=1.5), zero-pad, fp32 in/out.
// MFMA separable conv (layout verified exact in R7/R8):
//   h-blur: C[row][n] = A[row][k] x Wh[k][n], A[row][k]=u(row, c0+k-8), Wh[k][n]=g[k-n-3]
//   v-blur: C[col][n] = AT[col][k] x Wv[k][n], AT via LDS transpose, Wv[k][n]=g[k-n]
// R9: single-buffered ldsT (20.5 KB -> 5 blocks/CU), XOR bank swizzle on the
// transpose scratch, pkrtz packed f32->f16 converts. No barriers in main loop.

typedef _Float16 half8 __attribute__((ext_vector_type(8)));
typedef _Float16 half4v __attribute__((ext_vector_type(4)));
typedef __fp16 pk16 __attribute__((ext_vector_type(2)));   // pkrtz native type
typedef float f32x4 __attribute__((ext_vector_type(4)));
typedef float f32x8 __attribute__((ext_vector_type(8)));

#define IMG_W   512
#define IMG_H   512
#define NPLANES 48
#define BR      16                  // output rows per block
#define TP      40                  // ldsT k-pitch (halves); 80 B = 5*16 aligned
#define GRX     (IMG_H / BR)        // 32
#define NBLK    (GRX * NPLANES)     // 1536

__global__ __launch_bounds__(256, 5)
void dssim_main(const float* __restrict__ xin, const float* __restrict__ yin,
                float* __restrict__ partial) {
    __shared__ _Float16 ldsT[4][4][16][TP];   // [wave][ch][col][k]  20.5 KB
    __shared__ float wpart[4];

    const int t    = threadIdx.x;
    const int lane = t & 63;
    const int wid  = t >> 6;
    const int bn   = lane & 15;          // fragment row/col owner
    const int jg   = lane >> 4;          // k-chunk
    const int swz  = (bn & 8) << 1;      // XOR on k-index (halves): sep. bn vs bn+8
    const int r0   = blockIdx.x * BR;
    const size_t pbase = (size_t)blockIdx.y * (IMG_W * IMG_H);
    const float* __restrict__ xp = xin + pbase;
    const float* __restrict__ yp = yin + pbase;

    // gaussian normalization
    float ginv;
    {
        float s = 0.f;
#pragma unroll
        for (int i = 0; i < 11; ++i) {
            float d = (float)(i - 5);
            s += expf(-(d * d) * (1.0f / 4.5f));
        }
        ginv = 1.0f / s;
    }

    // banded weight fragments (B-operand: lane holds B[8*jg+j][bn])
    half8 whF, wvF;
#pragma unroll
    for (int j = 0; j < 8; ++j) {
        const int k = 8 * jg + j;
        const int dh = k - bn - 3;       // h band: g[k-n-3]
        const int dv = k - bn;           // v band: g[k-n]
        float wh = 0.f, wv = 0.f;
        if (dh >= 0 && dh < 11) {
            const float d = (float)(dh - 5);
            wh = ginv * expf(-(d * d) * (1.0f / 4.5f));
        }
        if (dv >= 0 && dv < 11) {
            const float d = (float)(dv - 5);
            wv = ginv * expf(-(d * d) * (1.0f / 4.5f));
        }
        whF[j] = (_Float16)wh;
        wvF[j] = (_Float16)wv;
    }

    // row addressing (iteration-invariant): rt0 rows bn, rt1 rows 16+bn
    const int gr0 = r0 - 5 + bn;
    const bool rowok0 = (gr0 >= 0) && (gr0 < IMG_H);
    const int gr1 = r0 + 11 + bn;
    const bool rowok1 = (bn < 10) && (gr1 < IMG_H);
    const size_t row0 = (size_t)(rowok0 ? gr0 : 0) * IMG_W;
    const size_t row1 = (size_t)(rowok1 ? gr1 : 0) * IMG_W;

    const f32x8 z8 = {0.f, 0.f, 0.f, 0.f, 0.f, 0.f, 0.f, 0.f};
    const f32x4 zf = {0.f, 0.f, 0.f, 0.f};
    const float C1 = 0.0001f, C2 = 0.0009f;
    float lsum = 0.f;

    f32x8 xs0, ys0, xs1, ys1;          // staged raw rows (named, static)

    // issue global loads for col-tile ii (k-window cols c0-8 .. c0+23)
#define LOADI(ii)                                                           \
    {                                                                       \
        const int col = (((wid + 4 * (ii)) << 4) + 8 * jg) - 8;             \
        const bool colok = (col >= 0) && (col < IMG_W);                     \
        const size_t co = (size_t)(colok ? col : 0);                        \
        const bool ok0 = colok && rowok0, ok1 = colok && rowok1;            \
        xs0 = ok0 ? *(const f32x8*)(xp + row0 + co) : z8;                   \
        ys0 = ok0 ? *(const f32x8*)(yp + row0 + co) : z8;                   \
        xs1 = ok1 ? *(const f32x8*)(xp + row1 + co) : z8;                   \
        ys1 = ok1 ? *(const f32x8*)(yp + row1 + co) : z8;                   \
    }

    // h-blur both row-tiles of col-tile ii into ldsT (single buffer)
#define HCOMPI(ii)                                                          \
    {                                                                       \
        _Pragma("unroll")                                                   \
        for (int rt = 0; rt < 2; ++rt) {                                    \
            const f32x8 xv = rt ? xs1 : xs0;                                \
            const f32x8 yv = rt ? ys1 : ys0;                                \
            half8 aU, aW;                                                   \
            _Pragma("unroll")                                               \
            for (int d = 0; d < 4; ++d) {                                   \
                const pk16 pu = __builtin_amdgcn_cvt_pkrtz(                 \
                    xv[2 * d] + yv[2 * d], xv[2 * d + 1] + yv[2 * d + 1]);  \
                const pk16 pw = __builtin_amdgcn_cvt_pkrtz(                 \
                    xv[2 * d] - yv[2 * d], xv[2 * d + 1] - yv[2 * d + 1]);  \
                aU[2 * d] = (_Float16)pu[0]; aU[2 * d + 1] = (_Float16)pu[1]; \
                aW[2 * d] = (_Float16)pw[0]; aW[2 * d + 1] = (_Float16)pw[1]; \
            }                                                               \
            const half8 aU2 = aU * aU;                                      \
            const half8 aW2 = aW * aW;                                      \
            const f32x4 cU  = __builtin_amdgcn_mfma_f32_16x16x32_f16(aU,  whF, zf, 0, 0, 0); \
            const f32x4 cW  = __builtin_amdgcn_mfma_f32_16x16x32_f16(aW,  whF, zf, 0, 0, 0); \
            const f32x4 cU2 = __builtin_amdgcn_mfma_f32_16x16x32_f16(aU2, whF, zf, 0, 0, 0); \
            const f32x4 cW2 = __builtin_amdgcn_mfma_f32_16x16x32_f16(aW2, whF, zf, 0, 0, 0); \
            half4v hU, hW, hU2, hW2;                                        \
            _Pragma("unroll")                                               \
            for (int q = 0; q < 2; ++q) {                                   \
                const pk16 p0 = __builtin_amdgcn_cvt_pkrtz(cU[2*q],  cU[2*q+1]);  \
                const pk16 p1 = __builtin_amdgcn_cvt_pkrtz(cW[2*q],  cW[2*q+1]);  \
                const pk16 p2 = __builtin_amdgcn_cvt_pkrtz(cU2[2*q], cU2[2*q+1]); \
                const pk16 p3 = __builtin_amdgcn_cvt_pkrtz(cW2[2*q], cW2[2*q+1]); \
                hU[2*q]  = (_Float16)p0[0]; hU[2*q+1]  = (_Float16)p0[1];   \
                hW[2*q]  = (_Float16)p1[0]; hW[2*q+1]  = (_Float16)p1[1];   \
                hU2[2*q] = (_Float16)p2[0]; hU2[2*q+1] = (_Float16)p2[1];   \
                hW2[2*q] = (_Float16)p3[0]; hW2[2*q+1] = (_Float16)p3[1];   \
            }                                                               \
            const int kk = (16 * rt + 4 * jg) ^ swz;                        \
            *(half4v*)&ldsT[wid][0][bn][kk] = hU;                           \
            *(half4v*)&ldsT[wid][1][bn][kk] = hW;                           \
            *(half4v*)&ldsT[wid][2][bn][kk] = hU2;                          \
            *(half4v*)&ldsT[wid][3][bn][kk] = hW2;                          \
        }                                                                   \
    }

    // v-blur col-tile ii from ldsT + ssim epilogue
#define VBLURI(ii)                                                          \
    {                                                                       \
        const int kb = (8 * jg) ^ swz;                                      \
        const half8 aTU  = *(const half8*)&ldsT[wid][0][bn][kb];            \
        const half8 aTW  = *(const half8*)&ldsT[wid][1][bn][kb];            \
        const half8 aTU2 = *(const half8*)&ldsT[wid][2][bn][kb];            \
        const half8 aTW2 = *(const half8*)&ldsT[wid][3][bn][kb];            \
        const f32x4 accU = __builtin_amdgcn_mfma_f32_16x16x32_f16(aTU,  wvF, zf, 0, 0, 0); \
        const f32x4 accW = __builtin_amdgcn_mfma_f32_16x16x32_f16(aTW,  wvF, zf, 0, 0, 0); \
        const f32x4 accP = __builtin_amdgcn_mfma_f32_16x16x32_f16(aTU2, wvF, zf, 0, 0, 0); \
        const f32x4 accQ = __builtin_amdgcn_mfma_f32_16x16x32_f16(aTW2, wvF, zf, 0, 0, 0); \
        _Pragma("unroll")                                                   \
        for (int q = 0; q < 4; ++q) {                                       \
            const float U = accU[q], W = accW[q];                           \
            const float P = accP[q], Q = accQ[q];                           \
            const float U2 = U * U, W2 = W * W;                             \
            const float A = 0.5f * (U2 + W2);                               \
            const float B = 0.5f * (U2 - W2);                               \
            const float den2 = fmaf(0.5f, P + Q, -A) + C2;                  \
            const float num2 = fmaf(0.5f, P - Q, -B) + C2;                  \
            lsum += (B + C1) * num2 * __builtin_amdgcn_rcpf((A + C1) * den2); \
        }                                                                   \
    }

    // software pipeline: load(i+1) || vblur(i), no barriers
    LOADI(0);
    HCOMPI(0);
#pragma unroll
    for (int i = 0; i < 8; ++i) {
        if (i + 1 < 8) LOADI(i + 1);
        VBLURI(i);
        if (i + 1 < 8) HCOMPI(i + 1);
    }

    // ---- block reduction ----
#pragma unroll
    for (int off = 32; off >= 1; off >>= 1)
        lsum += __shfl_down(lsum, off, 64);
    if (lane == 0) wpart[wid] = lsum;
    __syncthreads();
    if (t == 0) {
        partial[(size_t)blockIdx.y * GRX + blockIdx.x] =
            wpart[0] + wpart[1] + wpart[2] + wpart[3];
    }
}

__global__ __launch_bounds__(256)
void dssim_final(const float* __restrict__ partial, float* __restrict__ out) {
    __shared__ double wsum[4];
    double s = 0.0;
    for (int i = threadIdx.x; i < NBLK; i += 256) s += (double)partial[i];
#pragma unroll
    for (int off = 32; off >= 1; off >>= 1)
        s += __shfl_down(s, off, 64);
    if ((threadIdx.x & 63) == 0) wsum[threadIdx.x >> 6] = s;
    __syncthreads();
    if (threadIdx.x == 0) {
        const double tot = wsum[0] + wsum[1] + wsum[2] + wsum[3];
        out[0] = (float)(1.0 - tot / 12582912.0);
    }
}

extern "C" void kernel_launch(void* const* d_in, const int* in_sizes, int n_in,
                              void* d_out, int out_size, void* d_ws, size_t ws_size,
                              hipStream_t stream) {
    const float* x = (const float*)d_in[0];
    const float* y = (const float*)d_in[1];
    float* out = (float*)d_out;
    float* partial = (float*)d_ws;   // NBLK*4 = 6 KiB

    dim3 grid(GRX, NPLANES);         // 32 x 48 = 1536 blocks
    dim3 block(256);
    dssim_main<<<grid, block, 0, stream>>>(x, y, partial);
    dssim_final<<<1, block, 0, stream>>>(partial, out);
}

// Round 11
// 84.346 us; speedup vs baseline: 1.3434x; 1.3434x over previous
//
#include <hip/hip_runtime.h>

// DSSIM = 1 - mean(SSIM), 11x11 gaussian (sigma=1.5), zero-pad, fp32 in/out.
// MFMA separable conv (layout verified exact in R7/R8):
//   h-blur: C[row][n] = A[row][k] x Wh[k][n], A[row][k]=u(row, c0+k-8), Wh[k][n]=g[k-n-3]
//   v-blur: C[col][n] = AT[col][k] x Wv[k][n], AT via LDS transpose, Wv[k][n]=g[k-n]
// R11: == R10 but __launch_bounds__(256,4) — the ,5 VGPR cap (~96) forced the
// f32x8 staging registers to scratch (WRITE_SIZE 153 MB). Cap 128 instead.

typedef _Float16 half8 __attribute__((ext_vector_type(8)));
typedef _Float16 half4v __attribute__((ext_vector_type(4)));
typedef __fp16 pk16 __attribute__((ext_vector_type(2)));   // pkrtz native type
typedef float f32x4 __attribute__((ext_vector_type(4)));
typedef float f32x8 __attribute__((ext_vector_type(8)));

#define IMG_W   512
#define IMG_H   512
#define NPLANES 48
#define BR      16                  // output rows per block
#define TP      40                  // ldsT k-pitch (halves); 80 B = 5*16 aligned
#define GRX     (IMG_H / BR)        // 32
#define NBLK    (GRX * NPLANES)     // 1536

__global__ __launch_bounds__(256, 4)
void dssim_main(const float* __restrict__ xin, const float* __restrict__ yin,
                float* __restrict__ partial) {
    __shared__ _Float16 ldsT[4][4][16][TP];   // [wave][ch][col][k]  20.5 KB
    __shared__ float wpart[4];

    const int t    = threadIdx.x;
    const int lane = t & 63;
    const int wid  = t >> 6;
    const int bn   = lane & 15;          // fragment row/col owner
    const int jg   = lane >> 4;          // k-chunk
    const int swz  = (bn & 8) << 1;      // XOR on k-index (halves): sep. bn vs bn+8
    const int r0   = blockIdx.x * BR;
    const size_t pbase = (size_t)blockIdx.y * (IMG_W * IMG_H);
    const float* __restrict__ xp = xin + pbase;
    const float* __restrict__ yp = yin + pbase;

    // gaussian normalization
    float ginv;
    {
        float s = 0.f;
#pragma unroll
        for (int i = 0; i < 11; ++i) {
            float d = (float)(i - 5);
            s += expf(-(d * d) * (1.0f / 4.5f));
        }
        ginv = 1.0f / s;
    }

    // banded weight fragments (B-operand: lane holds B[8*jg+j][bn])
    half8 whF, wvF;
#pragma unroll
    for (int j = 0; j < 8; ++j) {
        const int k = 8 * jg + j;
        const int dh = k - bn - 3;       // h band: g[k-n-3]
        const int dv = k - bn;           // v band: g[k-n]
        float wh = 0.f, wv = 0.f;
        if (dh >= 0 && dh < 11) {
            const float d = (float)(dh - 5);
            wh = ginv * expf(-(d * d) * (1.0f / 4.5f));
        }
        if (dv >= 0 && dv < 11) {
            const float d = (float)(dv - 5);
            wv = ginv * expf(-(d * d) * (1.0f / 4.5f));
        }
        whF[j] = (_Float16)wh;
        wvF[j] = (_Float16)wv;
    }

    // row addressing (iteration-invariant): rt0 rows bn, rt1 rows 16+bn
    const int gr0 = r0 - 5 + bn;
    const bool rowok0 = (gr0 >= 0) && (gr0 < IMG_H);
    const int gr1 = r0 + 11 + bn;
    const bool rowok1 = (bn < 10) && (gr1 < IMG_H);
    const size_t row0 = (size_t)(rowok0 ? gr0 : 0) * IMG_W;
    const size_t row1 = (size_t)(rowok1 ? gr1 : 0) * IMG_W;

    const f32x8 z8 = {0.f, 0.f, 0.f, 0.f, 0.f, 0.f, 0.f, 0.f};
    const f32x4 zf = {0.f, 0.f, 0.f, 0.f};
    const float C1 = 0.0001f, C2 = 0.0009f;
    float lsum = 0.f;

    f32x8 xs0, ys0, xs1, ys1;          // staged raw rows (named, static)

    // issue global loads for col-tile ii (k-window cols c0-8 .. c0+23)
#define LOADI(ii)                                                           \
    {                                                                       \
        const int col = (((wid + 4 * (ii)) << 4) + 8 * jg) - 8;             \
        const bool colok = (col >= 0) && (col < IMG_W);                     \
        const size_t co = (size_t)(colok ? col : 0);                        \
        const bool ok0 = colok && rowok0, ok1 = colok && rowok1;            \
        xs0 = ok0 ? *(const f32x8*)(xp + row0 + co) : z8;                   \
        ys0 = ok0 ? *(const f32x8*)(yp + row0 + co) : z8;                   \
        xs1 = ok1 ? *(const f32x8*)(xp + row1 + co) : z8;                   \
        ys1 = ok1 ? *(const f32x8*)(yp + row1 + co) : z8;                   \
    }

    // h-blur both row-tiles of col-tile ii into ldsT (single buffer)
#define HCOMPI(ii)                                                          \
    {                                                                       \
        _Pragma("unroll")                                                   \
        for (int rt = 0; rt < 2; ++rt) {                                    \
            const f32x8 xv = rt ? xs1 : xs0;                                \
            const f32x8 yv = rt ? ys1 : ys0;                                \
            half8 aU, aW;                                                   \
            _Pragma("unroll")                                               \
            for (int d = 0; d < 4; ++d) {                                   \
                const pk16 pu = __builtin_amdgcn_cvt_pkrtz(                 \
                    xv[2 * d] + yv[2 * d], xv[2 * d + 1] + yv[2 * d + 1]);  \
                const pk16 pw = __builtin_amdgcn_cvt_pkrtz(                 \
                    xv[2 * d] - yv[2 * d], xv[2 * d + 1] - yv[2 * d + 1]);  \
                aU[2 * d] = (_Float16)pu[0]; aU[2 * d + 1] = (_Float16)pu[1]; \
                aW[2 * d] = (_Float16)pw[0]; aW[2 * d + 1] = (_Float16)pw[1]; \
            }                                                               \
            const half8 aU2 = aU * aU;                                      \
            const half8 aW2 = aW * aW;                                      \
            const f32x4 cU  = __builtin_amdgcn_mfma_f32_16x16x32_f16(aU,  whF, zf, 0, 0, 0); \
            const f32x4 cW  = __builtin_amdgcn_mfma_f32_16x16x32_f16(aW,  whF, zf, 0, 0, 0); \
            const f32x4 cU2 = __builtin_amdgcn_mfma_f32_16x16x32_f16(aU2, whF, zf, 0, 0, 0); \
            const f32x4 cW2 = __builtin_amdgcn_mfma_f32_16x16x32_f16(aW2, whF, zf, 0, 0, 0); \
            half4v hU, hW, hU2, hW2;                                        \
            _Pragma("unroll")                                               \
            for (int q = 0; q < 2; ++q) {                                   \
                const pk16 p0 = __builtin_amdgcn_cvt_pkrtz(cU[2*q],  cU[2*q+1]);  \
                const pk16 p1 = __builtin_amdgcn_cvt_pkrtz(cW[2*q],  cW[2*q+1]);  \
                const pk16 p2 = __builtin_amdgcn_cvt_pkrtz(cU2[2*q], cU2[2*q+1]); \
                const pk16 p3 = __builtin_amdgcn_cvt_pkrtz(cW2[2*q], cW2[2*q+1]); \
                hU[2*q]  = (_Float16)p0[0]; hU[2*q+1]  = (_Float16)p0[1];   \
                hW[2*q]  = (_Float16)p1[0]; hW[2*q+1]  = (_Float16)p1[1];   \
                hU2[2*q] = (_Float16)p2[0]; hU2[2*q+1] = (_Float16)p2[1];   \
                hW2[2*q] = (_Float16)p3[0]; hW2[2*q+1] = (_Float16)p3[1];   \
            }                                                               \
            const int kk = (16 * rt + 4 * jg) ^ swz;                        \
            *(half4v*)&ldsT[wid][0][bn][kk] = hU;                           \
            *(half4v*)&ldsT[wid][1][bn][kk] = hW;                           \
            *(half4v*)&ldsT[wid][2][bn][kk] = hU2;                          \
            *(half4v*)&ldsT[wid][3][bn][kk] = hW2;                          \
        }                                                                   \
    }

    // v-blur col-tile ii from ldsT + ssim epilogue
#define VBLURI(ii)                                                          \
    {                                                                       \
        const int kb = (8 * jg) ^ swz;                                      \
        const half8 aTU  = *(const half8*)&ldsT[wid][0][bn][kb];            \
        const half8 aTW  = *(const half8*)&ldsT[wid][1][bn][kb];            \
        const half8 aTU2 = *(const half8*)&ldsT[wid][2][bn][kb];            \
        const half8 aTW2 = *(const half8*)&ldsT[wid][3][bn][kb];            \
        const f32x4 accU = __builtin_amdgcn_mfma_f32_16x16x32_f16(aTU,  wvF, zf, 0, 0, 0); \
        const f32x4 accW = __builtin_amdgcn_mfma_f32_16x16x32_f16(aTW,  wvF, zf, 0, 0, 0); \
        const f32x4 accP = __builtin_amdgcn_mfma_f32_16x16x32_f16(aTU2, wvF, zf, 0, 0, 0); \
        const f32x4 accQ = __builtin_amdgcn_mfma_f32_16x16x32_f16(aTW2, wvF, zf, 0, 0, 0); \
        _Pragma("unroll")                                                   \
        for (int q = 0; q < 4; ++q) {                                       \
            const float U = accU[q], W = accW[q];                           \
            const float P = accP[q], Q = accQ[q];                           \
            const float U2 = U * U, W2 = W * W;                             \
            const float A = 0.5f * (U2 + W2);                               \
            const float B = 0.5f * (U2 - W2);                               \
            const float den2 = fmaf(0.5f, P + Q, -A) + C2;                  \
            const float num2 = fmaf(0.5f, P - Q, -B) + C2;                  \
            lsum += (B + C1) * num2 * __builtin_amdgcn_rcpf((A + C1) * den2); \
        }                                                                   \
    }

    // software pipeline: load(i+1) || vblur(i), no barriers
    LOADI(0);
    HCOMPI(0);
#pragma unroll
    for (int i = 0; i < 8; ++i) {
        if (i + 1 < 8) LOADI(i + 1);
        VBLURI(i);
        if (i + 1 < 8) HCOMPI(i + 1);
    }

    // ---- block reduction ----
#pragma unroll
    for (int off = 32; off >= 1; off >>= 1)
        lsum += __shfl_down(lsum, off, 64);
    if (lane == 0) wpart[wid] = lsum;
    __syncthreads();
    if (t == 0) {
        partial[(size_t)blockIdx.y * GRX + blockIdx.x] =
            wpart[0] + wpart[1] + wpart[2] + wpart[3];
    }
}

__global__ __launch_bounds__(256)
void dssim_final(const float* __restrict__ partial, float* __restrict__ out) {
    __shared__ double wsum[4];
    double s = 0.0;
    for (int i = threadIdx.x; i < NBLK; i += 256) s += (double)partial[i];
#pragma unroll
    for (int off = 32; off >= 1; off >>= 1)
        s += __shfl_down(s, off, 64);
    if ((threadIdx.x & 63) == 0) wsum[threadIdx.x >> 6] = s;
    __syncthreads();
    if (threadIdx.x == 0) {
        const double tot = wsum[0] + wsum[1] + wsum[2] + wsum[3];
        out[0] = (float)(1.0 - tot / 12582912.0);
    }
}

extern "C" void kernel_launch(void* const* d_in, const int* in_sizes, int n_in,
                              void* d_out, int out_size, void* d_ws, size_t ws_size,
                              hipStream_t stream) {
    const float* x = (const float*)d_in[0];
    const float* y = (const float*)d_in[1];
    float* out = (float*)d_out;
    float* partial = (float*)d_ws;   // NBLK*4 = 6 KiB

    dim3 grid(GRX, NPLANES);         // 32 x 48 = 1536 blocks
    dim3 block(256);
    dssim_main<<<grid, block, 0, stream>>>(x, y, partial);
    dssim_final<<<1, block, 0, stream>>>(partial, out);
}

// Round 12
// 48.278 us; speedup vs baseline: 2.3471x; 1.7471x over previous
//
#include <hip/hip_runtime.h>

// DSSIM = 1 - mean(SSIM), 11x11 gaussian (sigma=1.5), zero-pad, fp32 in/out.
// MFMA separable conv (layout verified exact in R7/R8):
//   h-blur: C[row][n] = A[row][k] x Wh[k][n], A[row][k]=u(row, c0+k-8), Wh[k][n]=g[k-n-3]
//   v-blur: C[col][n] = AT[col][k] x Wv[k][n], AT via LDS transpose, Wv[k][n]=g[k-n]
// R12: single-buffered ldsT (20.5 KB) + __launch_bounds__(256,3) — the only
// spill-free bound for this body (R10 ,5 and R11 ,4 both spilled the f32x8
// staging tile; R8 ,3 ran 84 VGPR / 49 KB writes). Occupancy gain from LDS.

typedef _Float16 half8 __attribute__((ext_vector_type(8)));
typedef _Float16 half4v __attribute__((ext_vector_type(4)));
typedef __fp16 pk16 __attribute__((ext_vector_type(2)));   // pkrtz native type
typedef float f32x4 __attribute__((ext_vector_type(4)));
typedef float f32x8 __attribute__((ext_vector_type(8)));

#define IMG_W   512
#define IMG_H   512
#define NPLANES 48
#define BR      16                  // output rows per block
#define TP      40                  // ldsT k-pitch (halves); 80 B = 5*16 aligned
#define GRX     (IMG_H / BR)        // 32
#define NBLK    (GRX * NPLANES)     // 1536

__global__ __launch_bounds__(256, 3)
void dssim_main(const float* __restrict__ xin, const float* __restrict__ yin,
                float* __restrict__ partial) {
    __shared__ _Float16 ldsT[4][4][16][TP];   // [wave][ch][col][k]  20.5 KB
    __shared__ float wpart[4];

    const int t    = threadIdx.x;
    const int lane = t & 63;
    const int wid  = t >> 6;
    const int bn   = lane & 15;          // fragment row/col owner
    const int jg   = lane >> 4;          // k-chunk
    const int swz  = (bn & 8) << 1;      // XOR on k-index (halves): sep. bn vs bn+8
    const int r0   = blockIdx.x * BR;
    const size_t pbase = (size_t)blockIdx.y * (IMG_W * IMG_H);
    const float* __restrict__ xp = xin + pbase;
    const float* __restrict__ yp = yin + pbase;

    // gaussian normalization
    float ginv;
    {
        float s = 0.f;
#pragma unroll
        for (int i = 0; i < 11; ++i) {
            float d = (float)(i - 5);
            s += expf(-(d * d) * (1.0f / 4.5f));
        }
        ginv = 1.0f / s;
    }

    // banded weight fragments (B-operand: lane holds B[8*jg+j][bn])
    half8 whF, wvF;
#pragma unroll
    for (int j = 0; j < 8; ++j) {
        const int k = 8 * jg + j;
        const int dh = k - bn - 3;       // h band: g[k-n-3]
        const int dv = k - bn;           // v band: g[k-n]
        float wh = 0.f, wv = 0.f;
        if (dh >= 0 && dh < 11) {
            const float d = (float)(dh - 5);
            wh = ginv * expf(-(d * d) * (1.0f / 4.5f));
        }
        if (dv >= 0 && dv < 11) {
            const float d = (float)(dv - 5);
            wv = ginv * expf(-(d * d) * (1.0f / 4.5f));
        }
        whF[j] = (_Float16)wh;
        wvF[j] = (_Float16)wv;
    }

    // row addressing (iteration-invariant): rt0 rows bn, rt1 rows 16+bn
    const int gr0 = r0 - 5 + bn;
    const bool rowok0 = (gr0 >= 0) && (gr0 < IMG_H);
    const int gr1 = r0 + 11 + bn;
    const bool rowok1 = (bn < 10) && (gr1 < IMG_H);
    const size_t row0 = (size_t)(rowok0 ? gr0 : 0) * IMG_W;
    const size_t row1 = (size_t)(rowok1 ? gr1 : 0) * IMG_W;

    const f32x8 z8 = {0.f, 0.f, 0.f, 0.f, 0.f, 0.f, 0.f, 0.f};
    const f32x4 zf = {0.f, 0.f, 0.f, 0.f};
    const float C1 = 0.0001f, C2 = 0.0009f;
    float lsum = 0.f;

    f32x8 xs0, ys0, xs1, ys1;          // staged raw rows (named, static)

    // issue global loads for col-tile ii (k-window cols c0-8 .. c0+23)
#define LOADI(ii)                                                           \
    {                                                                       \
        const int col = (((wid + 4 * (ii)) << 4) + 8 * jg) - 8;             \
        const bool colok = (col >= 0) && (col < IMG_W);                     \
        const size_t co = (size_t)(colok ? col : 0);                        \
        const bool ok0 = colok && rowok0, ok1 = colok && rowok1;            \
        xs0 = ok0 ? *(const f32x8*)(xp + row0 + co) : z8;                   \
        ys0 = ok0 ? *(const f32x8*)(yp + row0 + co) : z8;                   \
        xs1 = ok1 ? *(const f32x8*)(xp + row1 + co) : z8;                   \
        ys1 = ok1 ? *(const f32x8*)(yp + row1 + co) : z8;                   \
    }

    // h-blur both row-tiles of col-tile ii into ldsT (single buffer)
#define HCOMPI(ii)                                                          \
    {                                                                       \
        _Pragma("unroll")                                                   \
        for (int rt = 0; rt < 2; ++rt) {                                    \
            const f32x8 xv = rt ? xs1 : xs0;                                \
            const f32x8 yv = rt ? ys1 : ys0;                                \
            half8 aU, aW;                                                   \
            _Pragma("unroll")                                               \
            for (int d = 0; d < 4; ++d) {                                   \
                const pk16 pu = __builtin_amdgcn_cvt_pkrtz(                 \
                    xv[2 * d] + yv[2 * d], xv[2 * d + 1] + yv[2 * d + 1]);  \
                const pk16 pw = __builtin_amdgcn_cvt_pkrtz(                 \
                    xv[2 * d] - yv[2 * d], xv[2 * d + 1] - yv[2 * d + 1]);  \
                aU[2 * d] = (_Float16)pu[0]; aU[2 * d + 1] = (_Float16)pu[1]; \
                aW[2 * d] = (_Float16)pw[0]; aW[2 * d + 1] = (_Float16)pw[1]; \
            }                                                               \
            const half8 aU2 = aU * aU;                                      \
            const half8 aW2 = aW * aW;                                      \
            const f32x4 cU  = __builtin_amdgcn_mfma_f32_16x16x32_f16(aU,  whF, zf, 0, 0, 0); \
            const f32x4 cW  = __builtin_amdgcn_mfma_f32_16x16x32_f16(aW,  whF, zf, 0, 0, 0); \
            const f32x4 cU2 = __builtin_amdgcn_mfma_f32_16x16x32_f16(aU2, whF, zf, 0, 0, 0); \
            const f32x4 cW2 = __builtin_amdgcn_mfma_f32_16x16x32_f16(aW2, whF, zf, 0, 0, 0); \
            half4v hU, hW, hU2, hW2;                                        \
            _Pragma("unroll")                                               \
            for (int q = 0; q < 2; ++q) {                                   \
                const pk16 p0 = __builtin_amdgcn_cvt_pkrtz(cU[2*q],  cU[2*q+1]);  \
                const pk16 p1 = __builtin_amdgcn_cvt_pkrtz(cW[2*q],  cW[2*q+1]);  \
                const pk16 p2 = __builtin_amdgcn_cvt_pkrtz(cU2[2*q], cU2[2*q+1]); \
                const pk16 p3 = __builtin_amdgcn_cvt_pkrtz(cW2[2*q], cW2[2*q+1]); \
                hU[2*q]  = (_Float16)p0[0]; hU[2*q+1]  = (_Float16)p0[1];   \
                hW[2*q]  = (_Float16)p1[0]; hW[2*q+1]  = (_Float16)p1[1];   \
                hU2[2*q] = (_Float16)p2[0]; hU2[2*q+1] = (_Float16)p2[1];   \
                hW2[2*q] = (_Float16)p3[0]; hW2[2*q+1] = (_Float16)p3[1];   \
            }                                                               \
            const int kk = (16 * rt + 4 * jg) ^ swz;                        \
            *(half4v*)&ldsT[wid][0][bn][kk] = hU;                           \
            *(half4v*)&ldsT[wid][1][bn][kk] = hW;                           \
            *(half4v*)&ldsT[wid][2][bn][kk] = hU2;                          \
            *(half4v*)&ldsT[wid][3][bn][kk] = hW2;                          \
        }                                                                   \
    }

    // v-blur col-tile ii from ldsT + ssim epilogue
#define VBLURI(ii)                                                          \
    {                                                                       \
        const int kb = (8 * jg) ^ swz;                                      \
        const half8 aTU  = *(const half8*)&ldsT[wid][0][bn][kb];            \
        const half8 aTW  = *(const half8*)&ldsT[wid][1][bn][kb];            \
        const half8 aTU2 = *(const half8*)&ldsT[wid][2][bn][kb];            \
        const half8 aTW2 = *(const half8*)&ldsT[wid][3][bn][kb];            \
        const f32x4 accU = __builtin_amdgcn_mfma_f32_16x16x32_f16(aTU,  wvF, zf, 0, 0, 0); \
        const f32x4 accW = __builtin_amdgcn_mfma_f32_16x16x32_f16(aTW,  wvF, zf, 0, 0, 0); \
        const f32x4 accP = __builtin_amdgcn_mfma_f32_16x16x32_f16(aTU2, wvF, zf, 0, 0, 0); \
        const f32x4 accQ = __builtin_amdgcn_mfma_f32_16x16x32_f16(aTW2, wvF, zf, 0, 0, 0); \
        _Pragma("unroll")                                                   \
        for (int q = 0; q < 4; ++q) {                                       \
            const float U = accU[q], W = accW[q];                           \
            const float P = accP[q], Q = accQ[q];                           \
            const float U2 = U * U, W2 = W * W;                             \
            const float A = 0.5f * (U2 + W2);                               \
            const float B = 0.5f * (U2 - W2);                               \
            const float den2 = fmaf(0.5f, P + Q, -A) + C2;                  \
            const float num2 = fmaf(0.5f, P - Q, -B) + C2;                  \
            lsum += (B + C1) * num2 * __builtin_amdgcn_rcpf((A + C1) * den2); \
        }                                                                   \
    }

    // software pipeline: load(i+1) || vblur(i), no barriers
    LOADI(0);
    HCOMPI(0);
#pragma unroll
    for (int i = 0; i < 8; ++i) {
        if (i + 1 < 8) LOADI(i + 1);
        VBLURI(i);
        if (i + 1 < 8) HCOMPI(i + 1);
    }

    // ---- block reduction ----
#pragma unroll
    for (int off = 32; off >= 1; off >>= 1)
        lsum += __shfl_down(lsum, off, 64);
    if (lane == 0) wpart[wid] = lsum;
    __syncthreads();
    if (t == 0) {
        partial[(size_t)blockIdx.y * GRX + blockIdx.x] =
            wpart[0] + wpart[1] + wpart[2] + wpart[3];
    }
}

__global__ __launch_bounds__(256)
void dssim_final(const float* __restrict__ partial, float* __restrict__ out) {
    __shared__ double wsum[4];
    double s = 0.0;
    for (int i = threadIdx.x; i < NBLK; i += 256) s += (double)partial[i];
#pragma unroll
    for (int off = 32; off >= 1; off >>= 1)
        s += __shfl_down(s, off, 64);
    if ((threadIdx.x & 63) == 0) wsum[threadIdx.x >> 6] = s;
    __syncthreads();
    if (threadIdx.x == 0) {
        const double tot = wsum[0] + wsum[1] + wsum[2] + wsum[3];
        out[0] = (float)(1.0 - tot / 12582912.0);
    }
}

extern "C" void kernel_launch(void* const* d_in, const int* in_sizes, int n_in,
                              void* d_out, int out_size, void* d_ws, size_t ws_size,
                              hipStream_t stream) {
    const float* x = (const float*)d_in[0];
    const float* y = (const float*)d_in[1];
    float* out = (float*)d_out;
    float* partial = (float*)d_ws;   // NBLK*4 = 6 KiB

    dim3 grid(GRX, NPLANES);         // 32 x 48 = 1536 blocks
    dim3 block(256);
    dssim_main<<<grid, block, 0, stream>>>(x, y, partial);
    dssim_final<<<1, block, 0, stream>>>(partial, out);
}